// Round 1
// baseline (400.906 us; speedup 1.0000x reference)
//
#include <hip/hip_runtime.h>

// ---------------------------------------------------------------------------
// BlockCrossAttention on MI355X (gfx950).
// B=2, Ldec=8192 (nb=512 blocks of 16), Lenc=4096, D=1024, H=16, KV=4, HPG=4,
// DH=64, SCALE=0.125. All MFMA in bf16 (16x16x32), fp32 accumulate.
// Pipeline: transpose/cast weights -> cast enc -> pool hidden ->
//   GEMM Q/K/V (scatter epilogues) -> flash attention -> GEMM Wo -> broadcast.
// ---------------------------------------------------------------------------

typedef unsigned short u16;
typedef __attribute__((ext_vector_type(8))) __bf16 bf16x8;
typedef __attribute__((ext_vector_type(4))) float f32x4;

static __device__ __forceinline__ u16 f2bf(float f) {
    unsigned int u = __float_as_uint(f);
    u = (u + 0x7fffu + ((u >> 16) & 1u)) >> 16;   // RNE
    return (u16)u;
}

// ---------------- transpose + cast: in[K][N] fp32 -> out[N][K] bf16 --------
__global__ __launch_bounds__(256) void transpose_cast(const float* __restrict__ in,
                                                      u16* __restrict__ out,
                                                      int K, int N) {
    __shared__ float t[32][33];
    const int n0 = blockIdx.x * 32, k0 = blockIdx.y * 32;
    const int tx = threadIdx.x, ty = threadIdx.y;
#pragma unroll
    for (int i = 0; i < 4; ++i)
        t[ty + 8 * i][tx] = in[(size_t)(k0 + ty + 8 * i) * N + n0 + tx];
    __syncthreads();
#pragma unroll
    for (int i = 0; i < 4; ++i)
        out[(size_t)(n0 + ty + 8 * i) * K + k0 + tx] = f2bf(t[tx][ty + 8 * i]);
}

// ---------------- elementwise cast fp32 -> bf16, x4 ------------------------
__global__ __launch_bounds__(256) void cast4(const float* __restrict__ in,
                                             u16* __restrict__ out) {
    const int tid = blockIdx.x * 256 + threadIdx.x;
    float4 v = ((const float4*)in)[tid];
    ushort4 o;
    o.x = f2bf(v.x); o.y = f2bf(v.y); o.z = f2bf(v.z); o.w = f2bf(v.w);
    ((ushort4*)out)[tid] = o;
}

// ---------------- mean-pool 16 tokens -> bf16 [1024 rows][1024] ------------
__global__ __launch_bounds__(256) void pool_cast(const float* __restrict__ hid,
                                                 u16* __restrict__ pooled) {
    const int tid = blockIdx.x * 256 + threadIdx.x;   // 262144 total
    const int c4 = tid & 255;                         // col/4
    const int row = tid >> 8;                         // b*512 + n
    const float4* src = (const float4*)(hid + (size_t)row * 16 * 1024) + c4;
    float4 a = src[0];
#pragma unroll
    for (int t = 1; t < 16; ++t) {
        float4 b = src[(size_t)t * 256];
        a.x += b.x; a.y += b.y; a.z += b.z; a.w += b.w;
    }
    ushort4 o;
    o.x = f2bf(a.x * 0.0625f); o.y = f2bf(a.y * 0.0625f);
    o.z = f2bf(a.z * 0.0625f); o.w = f2bf(a.w * 0.0625f);
    *(ushort4*)(pooled + (size_t)row * 1024 + c4 * 4) = o;
}

// ---------------- GEMM, K=1024, 64x64 tile, bf16 MFMA ----------------------
// A: [M][1024] bf16 row-major.  Bt: [N][1024] bf16 (= B transposed).
// MODE 0: Q proj  -> out_bf[(((b*4+g)*4+qh)*512+n)*64+d], *SCALE
// MODE 1: K proj  -> out_bf[((b*4+g)*4096+l)*64+d]
// MODE 2: V proj  -> out_bf[((b*4+g)*64+d)*4096+l]   (transposed)
// MODE 3: O proj  -> out_f[m*1024+c]                  (fp32 block output)
template <int MODE>
__global__ __launch_bounds__(256) void gemm_k1024(const u16* __restrict__ A,
                                                  const u16* __restrict__ Bt,
                                                  u16* __restrict__ out_bf,
                                                  float* __restrict__ out_f) {
    const int m0 = blockIdx.x * 64, n0 = blockIdx.y * 64;
    __shared__ __align__(16) u16 sA[64 * 72];
    __shared__ __align__(16) u16 sB[64 * 72];
    const int t = threadIdx.x;
    const int w = t >> 6, lane = t & 63, quad = lane >> 4, r16 = lane & 15;
    f32x4 acc[4];
#pragma unroll
    for (int i = 0; i < 4; ++i) acc[i] = (f32x4){0.f, 0.f, 0.f, 0.f};

    for (int kt = 0; kt < 16; ++kt) {
        const int k0 = kt * 64;
        __syncthreads();
#pragma unroll
        for (int p = 0; p < 2; ++p) {
            const int idx = t + 256 * p, row = idx >> 3, ch = idx & 7;
            *(int4*)(sA + row * 72 + ch * 8) =
                *(const int4*)(A + (size_t)(m0 + row) * 1024 + k0 + ch * 8);
            *(int4*)(sB + row * 72 + ch * 8) =
                *(const int4*)(Bt + (size_t)(n0 + row) * 1024 + k0 + ch * 8);
        }
        __syncthreads();
#pragma unroll
        for (int kk = 0; kk < 2; ++kk) {
            const bf16x8 af = *(const bf16x8*)(sA + (16 * w + r16) * 72 + kk * 32 + quad * 8);
#pragma unroll
            for (int nt = 0; nt < 4; ++nt) {
                const bf16x8 bf = *(const bf16x8*)(sB + (nt * 16 + r16) * 72 + kk * 32 + quad * 8);
                acc[nt] = __builtin_amdgcn_mfma_f32_16x16x32_bf16(af, bf, acc[nt], 0, 0, 0);
            }
        }
    }
    // epilogue: C/D layout row = quad*4+r (within wave strip), col = lane&15
#pragma unroll
    for (int nt = 0; nt < 4; ++nt) {
#pragma unroll
        for (int r = 0; r < 4; ++r) {
            const int m = m0 + 16 * w + quad * 4 + r;
            const int c = n0 + nt * 16 + r16;
            const float v = acc[nt][r];
            if (MODE == 0) {
                const int b = m >> 9, nq = m & 511, g = c >> 8, qh = (c >> 6) & 3, d = c & 63;
                out_bf[((((size_t)(b * 4 + g) * 4 + qh) * 512 + nq) << 6) + d] = f2bf(v * 0.125f);
            } else if (MODE == 1) {
                const int b = m >> 12, l = m & 4095, g = c >> 6, d = c & 63;
                out_bf[(((size_t)(b * 4 + g) * 4096 + l) << 6) + d] = f2bf(v);
            } else if (MODE == 2) {
                const int b = m >> 12, l = m & 4095, g = c >> 6, d = c & 63;
                out_bf[((size_t)(b * 4 + g) * 64 + d) * 4096 + l] = f2bf(v);
            } else {
                out_f[(size_t)m * 1024 + c] = v;
            }
        }
    }
}

// ---------------- flash attention ------------------------------------------
// grid = 256: blockIdx.x = head(5b) * 8 + qtile(3b). 4 waves, each a 16-row
// Q strip. Per 64-wide K tile: S = Q K^T (MFMA), mask, online softmax,
// P -> LDS (C-layout -> A-layout round trip), O += P V (MFMA, V^T staged).
__global__ __launch_bounds__(256) void flash_attn(const u16* __restrict__ Qa,
                                                  const u16* __restrict__ Ka,
                                                  const u16* __restrict__ Vt,
                                                  const int* __restrict__ mask,
                                                  u16* __restrict__ attnout) {
    const int bx = blockIdx.x;
    const int tile = bx & 7, h = bx >> 3;
    const int b = h >> 4, g = (h >> 2) & 3, qh = h & 3;
    __shared__ __align__(16) u16 sK[64 * 72];
    __shared__ __align__(16) u16 sV[64 * 72];
    __shared__ __align__(16) u16 sP[4 * 16 * 72];
    const int t = threadIdx.x;
    const int w = t >> 6, lane = t & 63, quad = lane >> 4, r16 = lane & 15;

    bf16x8 aq[2];
    {
        const size_t qbase = ((((size_t)(b * 4 + g) * 4 + qh) * 512) + tile * 64 + 16 * w + r16) * 64;
#pragma unroll
        for (int kk = 0; kk < 2; ++kk)
            aq[kk] = *(const bf16x8*)(Qa + qbase + kk * 32 + quad * 8);
    }
    f32x4 o[4];
    float mrun[4], lrun[4];
#pragma unroll
    for (int i = 0; i < 4; ++i) {
        o[i] = (f32x4){0.f, 0.f, 0.f, 0.f};
        mrun[i] = -__builtin_inff();
        lrun[i] = 0.f;
    }
    const size_t kbase = (size_t)(b * 4 + g) * 4096 * 64;
    const size_t vbase = (size_t)(b * 4 + g) * 64 * 4096;
    const int* mr = mask + b * 4096;

    for (int kt = 0; kt < 64; ++kt) {
        const int l0 = kt * 64;
        __syncthreads();
#pragma unroll
        for (int p = 0; p < 2; ++p) {
            const int idx = t + 256 * p, row = idx >> 3, ch = idx & 7;
            *(int4*)(sK + row * 72 + ch * 8) =
                *(const int4*)(Ka + kbase + (size_t)(l0 + row) * 64 + ch * 8);
            *(int4*)(sV + row * 72 + ch * 8) =
                *(const int4*)(Vt + vbase + (size_t)row * 4096 + l0 + ch * 8);
        }
        __syncthreads();

        f32x4 s[4];
#pragma unroll
        for (int nt = 0; nt < 4; ++nt) s[nt] = (f32x4){0.f, 0.f, 0.f, 0.f};
#pragma unroll
        for (int kk = 0; kk < 2; ++kk) {
#pragma unroll
            for (int nt = 0; nt < 4; ++nt) {
                const bf16x8 bk = *(const bf16x8*)(sK + (nt * 16 + r16) * 72 + kk * 32 + quad * 8);
                s[nt] = __builtin_amdgcn_mfma_f32_16x16x32_bf16(aq[kk], bk, s[nt], 0, 0, 0);
            }
        }
        // mask: each lane's 4 values of s[nt] share column l = l0+nt*16+r16
#pragma unroll
        for (int nt = 0; nt < 4; ++nt) {
            if (mr[l0 + nt * 16 + r16] == 0) {
                s[nt][0] = -1e9f; s[nt][1] = -1e9f; s[nt][2] = -1e9f; s[nt][3] = -1e9f;
            }
        }
        // row max across 16 lanes of the quad
        float mx[4];
#pragma unroll
        for (int r = 0; r < 4; ++r)
            mx[r] = fmaxf(fmaxf(s[0][r], s[1][r]), fmaxf(s[2][r], s[3][r]));
#pragma unroll
        for (int off = 1; off < 16; off <<= 1)
#pragma unroll
            for (int r = 0; r < 4; ++r) mx[r] = fmaxf(mx[r], __shfl_xor(mx[r], off));

        float alpha[4], rs[4];
#pragma unroll
        for (int r = 0; r < 4; ++r) {
            const float mn = fmaxf(mrun[r], mx[r]);
            alpha[r] = __expf(mrun[r] - mn);
            mrun[r] = mn;
            rs[r] = 0.f;
        }
#pragma unroll
        for (int nt = 0; nt < 4; ++nt)
#pragma unroll
            for (int r = 0; r < 4; ++r) {
                const float p = __expf(s[nt][r] - mrun[r]);
                s[nt][r] = p;
                rs[r] += p;
            }
#pragma unroll
        for (int off = 1; off < 16; off <<= 1)
#pragma unroll
            for (int r = 0; r < 4; ++r) rs[r] += __shfl_xor(rs[r], off);
#pragma unroll
        for (int r = 0; r < 4; ++r) lrun[r] = lrun[r] * alpha[r] + rs[r];
#pragma unroll
        for (int dt = 0; dt < 4; ++dt)
#pragma unroll
            for (int r = 0; r < 4; ++r) o[dt][r] *= alpha[r];

        // P: C-layout regs -> LDS -> A-layout frags (same wave, no barrier)
        u16* Pw = sP + w * 16 * 72;
#pragma unroll
        for (int nt = 0; nt < 4; ++nt)
#pragma unroll
            for (int r = 0; r < 4; ++r)
                Pw[(quad * 4 + r) * 72 + nt * 16 + r16] = f2bf(s[nt][r]);
        bf16x8 pa[2];
#pragma unroll
        for (int kk = 0; kk < 2; ++kk)
            pa[kk] = *(const bf16x8*)(Pw + r16 * 72 + kk * 32 + quad * 8);
#pragma unroll
        for (int kk = 0; kk < 2; ++kk)
#pragma unroll
            for (int dt = 0; dt < 4; ++dt) {
                const bf16x8 bv = *(const bf16x8*)(sV + (dt * 16 + r16) * 72 + kk * 32 + quad * 8);
                o[dt] = __builtin_amdgcn_mfma_f32_16x16x32_bf16(pa[kk], bv, o[dt], 0, 0, 0);
            }
    }

    float inv[4];
#pragma unroll
    for (int r = 0; r < 4; ++r) inv[r] = 1.f / lrun[r];
    const int nbase = tile * 64 + 16 * w + quad * 4;
    const size_t obase = ((size_t)b * 512 + nbase) * 1024 + (g * 4 + qh) * 64;
#pragma unroll
    for (int r = 0; r < 4; ++r)
#pragma unroll
        for (int dt = 0; dt < 4; ++dt)
            attnout[obase + (size_t)r * 1024 + dt * 16 + r16] = f2bf(o[dt][r] * inv[r]);
}

// ---------------- broadcast block output x16 to token level ----------------
__global__ __launch_bounds__(256) void bcast_out(const float* __restrict__ blockout,
                                                 float* __restrict__ out) {
    const int tid = blockIdx.x * 256 + threadIdx.x;   // 4,194,304 float4s
    const int c4 = tid & 255;
    const int row = tid >> 8;                          // b*8192 + l
    const int b = row >> 13, l = row & 8191;
    ((float4*)out)[tid] = ((const float4*)blockout)[((size_t)(b * 512 + (l >> 4)) << 8) + c4];
}

// ---------------------------------------------------------------------------
extern "C" void kernel_launch(void* const* d_in, const int* in_sizes, int n_in,
                              void* d_out, int out_size, void* d_ws, size_t ws_size,
                              hipStream_t stream) {
    const float* hid  = (const float*)d_in[0];
    const float* enc  = (const float*)d_in[1];
    const int*   mask = (const int*)d_in[2];
    const float* Wq   = (const float*)d_in[3];
    const float* Wk   = (const float*)d_in[4];
    const float* Wv   = (const float*)d_in[5];
    const float* Wo   = (const float*)d_in[6];
    float* out = (float*)d_out;

    char* ws = (char*)d_ws;
    size_t off = 0;
    auto alloc = [&](size_t bytes) -> char* {
        char* p = ws + off;
        off += (bytes + 255) & ~(size_t)255;
        return p;
    };
    u16* Wq_t  = (u16*)alloc((size_t)1024 * 1024 * 2);
    u16* Wk_t  = (u16*)alloc((size_t)256 * 1024 * 2);
    u16* Wv_t  = (u16*)alloc((size_t)256 * 1024 * 2);
    u16* Wo_t  = (u16*)alloc((size_t)1024 * 1024 * 2);
    u16* encb  = (u16*)alloc((size_t)8192 * 1024 * 2);
    u16* poolb = (u16*)alloc((size_t)1024 * 1024 * 2);
    u16* Qa    = (u16*)alloc((size_t)1024 * 1024 * 2);
    u16* Ka    = (u16*)alloc((size_t)8 * 4096 * 64 * 2);
    u16* Va    = (u16*)alloc((size_t)8 * 4096 * 64 * 2);
    u16* attn  = (u16*)alloc((size_t)1024 * 1024 * 2);
    float* blk = (float*)alloc((size_t)1024 * 1024 * 4);

    transpose_cast<<<dim3(32, 32), dim3(32, 8), 0, stream>>>(Wq, Wq_t, 1024, 1024);
    transpose_cast<<<dim3(8, 32),  dim3(32, 8), 0, stream>>>(Wk, Wk_t, 1024, 256);
    transpose_cast<<<dim3(8, 32),  dim3(32, 8), 0, stream>>>(Wv, Wv_t, 1024, 256);
    transpose_cast<<<dim3(32, 32), dim3(32, 8), 0, stream>>>(Wo, Wo_t, 1024, 1024);
    cast4<<<8192, 256, 0, stream>>>(enc, encb);
    pool_cast<<<1024, 256, 0, stream>>>(hid, poolb);

    gemm_k1024<0><<<dim3(16, 16), 256, 0, stream>>>(poolb, Wq_t, Qa, nullptr);
    gemm_k1024<1><<<dim3(128, 4), 256, 0, stream>>>(encb, Wk_t, Ka, nullptr);
    gemm_k1024<2><<<dim3(128, 4), 256, 0, stream>>>(encb, Wv_t, Va, nullptr);

    flash_attn<<<256, 256, 0, stream>>>(Qa, Ka, Va, mask, attn);

    gemm_k1024<3><<<dim3(16, 16), 256, 0, stream>>>(attn, Wo_t, nullptr, blk);
    bcast_out<<<16384, 256, 0, stream>>>(blk, out);
}

// Round 2
// 326.464 us; speedup vs baseline: 1.2280x; 1.2280x over previous
//
#include <hip/hip_runtime.h>

// ---------------------------------------------------------------------------
// BlockCrossAttention on MI355X (gfx950).  Round 2: flash split-K (4 splits,
// 1024 WGs, 4 WG/CU), exp2-domain softmax (log2e folded into Q scale),
// fused K+V projection GEMM, merged prep/transpose launches.
// ---------------------------------------------------------------------------

typedef unsigned short u16;
typedef __attribute__((ext_vector_type(8))) __bf16 bf16x8;
typedef __attribute__((ext_vector_type(4))) float f32x4;

static __device__ __forceinline__ u16 f2bf(float f) {
    unsigned int u = __float_as_uint(f);
    u = (u + 0x7fffu + ((u >> 16) & 1u)) >> 16;   // RNE
    return (u16)u;
}

// ---------------- all 4 weight transposes in one launch --------------------
// in[K=1024][N] fp32 -> out[N(+rowoff)][1024] bf16
__global__ __launch_bounds__(256) void transpose_all(const float* __restrict__ Wq,
                                                     const float* __restrict__ Wk,
                                                     const float* __restrict__ Wv,
                                                     const float* __restrict__ Wo,
                                                     u16* __restrict__ Wq_t,
                                                     u16* __restrict__ Wkv_t,
                                                     u16* __restrict__ Wo_t) {
    int bid = blockIdx.x;
    const float* in; u16* out; int N, nbx, rowoff;
    if (bid < 1024)      { in = Wq; out = Wq_t;  N = 1024; nbx = 32; rowoff = 0; }
    else if (bid < 2048) { in = Wo; out = Wo_t;  N = 1024; nbx = 32; rowoff = 0; bid -= 1024; }
    else if (bid < 2304) { in = Wk; out = Wkv_t; N = 256;  nbx = 8;  rowoff = 0; bid -= 2048; }
    else                 { in = Wv; out = Wkv_t; N = 256;  nbx = 8;  rowoff = 256; bid -= 2304; }
    const int n0 = (bid % nbx) * 32, k0 = (bid / nbx) * 32;
    __shared__ float t[32][33];
    const int tx = threadIdx.x & 31, ty = threadIdx.x >> 5;
#pragma unroll
    for (int i = 0; i < 4; ++i)
        t[ty + 8 * i][tx] = in[(size_t)(k0 + ty + 8 * i) * N + n0 + tx];
    __syncthreads();
#pragma unroll
    for (int i = 0; i < 4; ++i)
        out[(size_t)(rowoff + n0 + ty + 8 * i) * 1024 + k0 + tx] = f2bf(t[tx][ty + 8 * i]);
}

// ---------------- enc cast + hidden mean-pool in one launch ----------------
__global__ __launch_bounds__(256) void prep_inputs(const float* __restrict__ enc,
                                                   const float* __restrict__ hid,
                                                   u16* __restrict__ encb,
                                                   u16* __restrict__ poolb) {
    const int bid = blockIdx.x;
    if (bid < 8192) {                                  // cast enc fp32->bf16 x4
        const int tid = bid * 256 + threadIdx.x;
        float4 v = ((const float4*)enc)[tid];
        ushort4 o;
        o.x = f2bf(v.x); o.y = f2bf(v.y); o.z = f2bf(v.z); o.w = f2bf(v.w);
        ((ushort4*)encb)[tid] = o;
    } else {                                           // mean-pool 16 tokens
        const int tid = (bid - 8192) * 256 + threadIdx.x;  // 262144
        const int c4 = tid & 255;
        const int row = tid >> 8;                      // b*512 + n
        const float4* src = (const float4*)(hid + (size_t)row * 16 * 1024) + c4;
        float4 a = src[0];
#pragma unroll
        for (int t = 1; t < 16; ++t) {
            float4 b = src[(size_t)t * 256];
            a.x += b.x; a.y += b.y; a.z += b.z; a.w += b.w;
        }
        ushort4 o;
        o.x = f2bf(a.x * 0.0625f); o.y = f2bf(a.y * 0.0625f);
        o.z = f2bf(a.z * 0.0625f); o.w = f2bf(a.w * 0.0625f);
        *(ushort4*)(poolb + (size_t)row * 1024 + c4 * 4) = o;
    }
}

// ---------------- GEMM, K=1024, 64x64 tile, bf16 MFMA ----------------------
// MODE 0: Q proj -> Qa[(((b*4+g)*4+qh)*512+n)*64+d], * 0.125*log2e (exp2 dom.)
// MODE 3: O proj -> out_f[m*1024+c] (fp32 block output)
// MODE 4: fused K|V proj (Bt = [Wk_t;Wv_t], N=512): c<256 -> Ka, else Va^T
template <int MODE>
__global__ __launch_bounds__(256) void gemm_k1024(const u16* __restrict__ A,
                                                  const u16* __restrict__ Bt,
                                                  u16* __restrict__ outK,
                                                  u16* __restrict__ outV,
                                                  float* __restrict__ out_f) {
    const int m0 = blockIdx.x * 64, n0 = blockIdx.y * 64;
    __shared__ __align__(16) u16 sA[64 * 72];
    __shared__ __align__(16) u16 sB[64 * 72];
    const int t = threadIdx.x;
    const int w = t >> 6, lane = t & 63, quad = lane >> 4, r16 = lane & 15;
    f32x4 acc[4];
#pragma unroll
    for (int i = 0; i < 4; ++i) acc[i] = (f32x4){0.f, 0.f, 0.f, 0.f};

    for (int kt = 0; kt < 16; ++kt) {
        const int k0 = kt * 64;
        __syncthreads();
#pragma unroll
        for (int p = 0; p < 2; ++p) {
            const int idx = t + 256 * p, row = idx >> 3, ch = idx & 7;
            *(int4*)(sA + row * 72 + ch * 8) =
                *(const int4*)(A + (size_t)(m0 + row) * 1024 + k0 + ch * 8);
            *(int4*)(sB + row * 72 + ch * 8) =
                *(const int4*)(Bt + (size_t)(n0 + row) * 1024 + k0 + ch * 8);
        }
        __syncthreads();
#pragma unroll
        for (int kk = 0; kk < 2; ++kk) {
            const bf16x8 af = *(const bf16x8*)(sA + (16 * w + r16) * 72 + kk * 32 + quad * 8);
#pragma unroll
            for (int nt = 0; nt < 4; ++nt) {
                const bf16x8 bf = *(const bf16x8*)(sB + (nt * 16 + r16) * 72 + kk * 32 + quad * 8);
                acc[nt] = __builtin_amdgcn_mfma_f32_16x16x32_bf16(af, bf, acc[nt], 0, 0, 0);
            }
        }
    }
#pragma unroll
    for (int nt = 0; nt < 4; ++nt) {
#pragma unroll
        for (int r = 0; r < 4; ++r) {
            const int m = m0 + 16 * w + quad * 4 + r;
            const int c = n0 + nt * 16 + r16;
            const float v = acc[nt][r];
            if (MODE == 0) {
                const int b = m >> 9, nq = m & 511, g = c >> 8, qh = (c >> 6) & 3, d = c & 63;
                // 0.125 * log2(e): softmax runs in exp2 domain
                outK[((((size_t)(b * 4 + g) * 4 + qh) * 512 + nq) << 6) + d] = f2bf(v * 0.180336880f);
            } else if (MODE == 4) {
                const int b = m >> 12, l = m & 4095;
                if (c < 256) {
                    const int g = c >> 6, d = c & 63;
                    outK[(((size_t)(b * 4 + g) * 4096 + l) << 6) + d] = f2bf(v);
                } else {
                    const int cc = c - 256, g = cc >> 6, d = cc & 63;
                    outV[((size_t)(b * 4 + g) * 64 + d) * 4096 + l] = f2bf(v);
                }
            } else {
                out_f[(size_t)m * 1024 + c] = v;
            }
        }
    }
}

// ---------------- flash attention, split-K ---------------------------------
// grid = 1024: bx = hq*4 + split; hq = head(5b)*8 + qtile(3b); split in [0,4).
// Each WG: 16 K-tiles of 64 tokens. Writes unnormalized O + (m,l) partials.
__global__ __launch_bounds__(256) void flash_attn_split(const u16* __restrict__ Qa,
                                                        const u16* __restrict__ Ka,
                                                        const u16* __restrict__ Vt,
                                                        const int* __restrict__ mask,
                                                        float* __restrict__ Opart,
                                                        float* __restrict__ mlpart) {
    const int bx = blockIdx.x;
    const int split = bx & 3, hq = bx >> 2;
    const int tile = hq & 7, h = hq >> 3;
    const int b = h >> 4, g = (h >> 2) & 3, qh = h & 3;
    __shared__ __align__(16) u16 sK[64 * 72];
    __shared__ __align__(16) u16 sV[64 * 72];
    __shared__ __align__(16) u16 sP[4 * 16 * 72];
    const int t = threadIdx.x;
    const int w = t >> 6, lane = t & 63, quad = lane >> 4, r16 = lane & 15;

    bf16x8 aq[2];
    {
        const size_t qbase = ((((size_t)(b * 4 + g) * 4 + qh) * 512) + tile * 64 + 16 * w + r16) * 64;
#pragma unroll
        for (int kk = 0; kk < 2; ++kk)
            aq[kk] = *(const bf16x8*)(Qa + qbase + kk * 32 + quad * 8);
    }
    f32x4 o[4];
    float mrun[4], lrun[4];
#pragma unroll
    for (int i = 0; i < 4; ++i) {
        o[i] = (f32x4){0.f, 0.f, 0.f, 0.f};
        mrun[i] = -__builtin_inff();
        lrun[i] = 0.f;
    }
    const size_t kbase = (size_t)(b * 4 + g) * 4096 * 64;
    const size_t vbase = (size_t)(b * 4 + g) * 64 * 4096;
    const int* mr = mask + b * 4096;

    for (int kt = split * 16; kt < split * 16 + 16; ++kt) {
        const int l0 = kt * 64;
        __syncthreads();
#pragma unroll
        for (int p = 0; p < 2; ++p) {
            const int idx = t + 256 * p, row = idx >> 3, ch = idx & 7;
            *(int4*)(sK + row * 72 + ch * 8) =
                *(const int4*)(Ka + kbase + (size_t)(l0 + row) * 64 + ch * 8);
            *(int4*)(sV + row * 72 + ch * 8) =
                *(const int4*)(Vt + vbase + (size_t)row * 4096 + l0 + ch * 8);
        }
        __syncthreads();

        f32x4 s[4];
#pragma unroll
        for (int nt = 0; nt < 4; ++nt) s[nt] = (f32x4){0.f, 0.f, 0.f, 0.f};
#pragma unroll
        for (int kk = 0; kk < 2; ++kk) {
#pragma unroll
            for (int nt = 0; nt < 4; ++nt) {
                const bf16x8 bk = *(const bf16x8*)(sK + (nt * 16 + r16) * 72 + kk * 32 + quad * 8);
                s[nt] = __builtin_amdgcn_mfma_f32_16x16x32_bf16(aq[kk], bk, s[nt], 0, 0, 0);
            }
        }
#pragma unroll
        for (int nt = 0; nt < 4; ++nt) {
            if (mr[l0 + nt * 16 + r16] == 0) {
                s[nt][0] = -1e9f; s[nt][1] = -1e9f; s[nt][2] = -1e9f; s[nt][3] = -1e9f;
            }
        }
        float mx[4];
#pragma unroll
        for (int r = 0; r < 4; ++r)
            mx[r] = fmaxf(fmaxf(s[0][r], s[1][r]), fmaxf(s[2][r], s[3][r]));
#pragma unroll
        for (int off = 1; off < 16; off <<= 1)
#pragma unroll
            for (int r = 0; r < 4; ++r) mx[r] = fmaxf(mx[r], __shfl_xor(mx[r], off));

        float alpha[4], rs[4];
#pragma unroll
        for (int r = 0; r < 4; ++r) {
            const float mn = fmaxf(mrun[r], mx[r]);
            alpha[r] = __builtin_amdgcn_exp2f(mrun[r] - mn);
            mrun[r] = mn;
            rs[r] = 0.f;
        }
#pragma unroll
        for (int nt = 0; nt < 4; ++nt)
#pragma unroll
            for (int r = 0; r < 4; ++r) {
                const float p = __builtin_amdgcn_exp2f(s[nt][r] - mrun[r]);
                s[nt][r] = p;
                rs[r] += p;
            }
#pragma unroll
        for (int off = 1; off < 16; off <<= 1)
#pragma unroll
            for (int r = 0; r < 4; ++r) rs[r] += __shfl_xor(rs[r], off);
#pragma unroll
        for (int r = 0; r < 4; ++r) lrun[r] = lrun[r] * alpha[r] + rs[r];
#pragma unroll
        for (int dt = 0; dt < 4; ++dt)
#pragma unroll
            for (int r = 0; r < 4; ++r) o[dt][r] *= alpha[r];

        u16* Pw = sP + w * 16 * 72;
#pragma unroll
        for (int nt = 0; nt < 4; ++nt)
#pragma unroll
            for (int r = 0; r < 4; ++r)
                Pw[(quad * 4 + r) * 72 + nt * 16 + r16] = f2bf(s[nt][r]);
        bf16x8 pa[2];
#pragma unroll
        for (int kk = 0; kk < 2; ++kk)
            pa[kk] = *(const bf16x8*)(Pw + r16 * 72 + kk * 32 + quad * 8);
#pragma unroll
        for (int kk = 0; kk < 2; ++kk)
#pragma unroll
            for (int dt = 0; dt < 4; ++dt) {
                const bf16x8 bv = *(const bf16x8*)(sV + (dt * 16 + r16) * 72 + kk * 32 + quad * 8);
                o[dt] = __builtin_amdgcn_mfma_f32_16x16x32_bf16(pa[kk], bv, o[dt], 0, 0, 0);
            }
    }

    // write unnormalized partials: Opart[(hq*4+split)*64+row][col], ml[row]
    const int rowb = 16 * w + quad * 4;
    const size_t pbase = ((size_t)(hq * 4 + split) * 64 + rowb) * 64;
#pragma unroll
    for (int r = 0; r < 4; ++r)
#pragma unroll
        for (int dt = 0; dt < 4; ++dt)
            Opart[pbase + (size_t)r * 64 + dt * 16 + r16] = o[dt][r];
    if (r16 == 0) {
#pragma unroll
        for (int r = 0; r < 4; ++r) {
            float2 ml = make_float2(mrun[r], lrun[r]);
            *(float2*)(mlpart + (((size_t)(hq * 4 + split) * 64 + rowb + r) << 1)) = ml;
        }
    }
}

// ---------------- combine split partials -> normalized attn (bf16) ---------
__global__ __launch_bounds__(256) void flash_combine(const float* __restrict__ Opart,
                                                     const float* __restrict__ mlpart,
                                                     u16* __restrict__ attnout) {
    const int hq = blockIdx.x;                  // [0,256)
    const int t = threadIdx.x;
    const int row = t >> 2, cg = t & 3;         // 16 cols per thread
    float m[4], l[4];
#pragma unroll
    for (int s = 0; s < 4; ++s) {
        const float2 ml = *(const float2*)(mlpart + (((size_t)(hq * 4 + s) * 64 + row) << 1));
        m[s] = ml.x; l[s] = ml.y;
    }
    const float M = fmaxf(fmaxf(m[0], m[1]), fmaxf(m[2], m[3]));
    float wgt[4], L = 0.f;
#pragma unroll
    for (int s = 0; s < 4; ++s) {
        wgt[s] = __builtin_amdgcn_exp2f(m[s] - M);
        L += wgt[s] * l[s];
    }
    const float invL = 1.f / L;
    float4 acc[4];
#pragma unroll
    for (int j = 0; j < 4; ++j) acc[j] = make_float4(0.f, 0.f, 0.f, 0.f);
#pragma unroll
    for (int s = 0; s < 4; ++s) {
        const float4* src = (const float4*)(Opart + ((size_t)(hq * 4 + s) * 64 + row) * 64 + cg * 16);
#pragma unroll
        for (int j = 0; j < 4; ++j) {
            float4 v = src[j];
            acc[j].x += wgt[s] * v.x; acc[j].y += wgt[s] * v.y;
            acc[j].z += wgt[s] * v.z; acc[j].w += wgt[s] * v.w;
        }
    }
    const int tile = hq & 7, h = hq >> 3;
    const int b = h >> 4, g = (h >> 2) & 3, qh = h & 3;
    const size_t obase = ((size_t)b * 512 + tile * 64 + row) * 1024 + (g * 4 + qh) * 64 + cg * 16;
#pragma unroll
    for (int j = 0; j < 4; ++j) {
        ushort4 ov;
        ov.x = f2bf(acc[j].x * invL); ov.y = f2bf(acc[j].y * invL);
        ov.z = f2bf(acc[j].z * invL); ov.w = f2bf(acc[j].w * invL);
        *(ushort4*)(attnout + obase + j * 4) = ov;
    }
}

// ---------------- broadcast block output x16 to token level ----------------
__global__ __launch_bounds__(256) void bcast_out(const float* __restrict__ blockout,
                                                 float* __restrict__ out) {
    const int tid = blockIdx.x * 256 + threadIdx.x;   // 4,194,304 float4s
    const int c4 = tid & 255;
    const int row = tid >> 8;                          // b*8192 + l
    const int b = row >> 13, l = row & 8191;
    ((float4*)out)[tid] = ((const float4*)blockout)[((size_t)(b * 512 + (l >> 4)) << 8) + c4];
}

// ---------------------------------------------------------------------------
extern "C" void kernel_launch(void* const* d_in, const int* in_sizes, int n_in,
                              void* d_out, int out_size, void* d_ws, size_t ws_size,
                              hipStream_t stream) {
    const float* hid  = (const float*)d_in[0];
    const float* enc  = (const float*)d_in[1];
    const int*   mask = (const int*)d_in[2];
    const float* Wq   = (const float*)d_in[3];
    const float* Wk   = (const float*)d_in[4];
    const float* Wv   = (const float*)d_in[5];
    const float* Wo   = (const float*)d_in[6];
    float* out = (float*)d_out;

    char* ws = (char*)d_ws;
    size_t off = 0;
    auto alloc = [&](size_t bytes) -> char* {
        char* p = ws + off;
        off += (bytes + 255) & ~(size_t)255;
        return p;
    };
    u16* Wq_t  = (u16*)alloc((size_t)1024 * 1024 * 2);
    u16* Wkv_t = (u16*)alloc((size_t)512 * 1024 * 2);      // [Wk_t; Wv_t]
    u16* Wo_t  = (u16*)alloc((size_t)1024 * 1024 * 2);
    u16* encb  = (u16*)alloc((size_t)8192 * 1024 * 2);     // 16 MB
    u16* poolb = (u16*)alloc((size_t)1024 * 1024 * 2);     // 2 MB
    u16* Qa    = (u16*)alloc((size_t)1024 * 1024 * 2);
    u16* Ka    = (u16*)alloc((size_t)8 * 4096 * 64 * 2);
    u16* Va    = (u16*)alloc((size_t)8 * 4096 * 64 * 2);
    u16* attn  = (u16*)alloc((size_t)1024 * 1024 * 2);
    float* blk = (float*)alloc((size_t)1024 * 1024 * 4);
    // aliases: dead after their GEMM consumers, reused by flash partials
    float* Opart  = (float*)encb;    // 16 MB needed, 16 MB available
    float* mlpart = (float*)poolb;   // 512 KB needed, 2 MB available

    transpose_all<<<2560, 256, 0, stream>>>(Wq, Wk, Wv, Wo, Wq_t, Wkv_t, Wo_t);
    prep_inputs<<<9216, 256, 0, stream>>>(enc, hid, encb, poolb);

    gemm_k1024<0><<<dim3(16, 16), 256, 0, stream>>>(poolb, Wq_t, Qa, nullptr, nullptr);
    gemm_k1024<4><<<dim3(128, 8), 256, 0, stream>>>(encb, Wkv_t, Ka, Va, nullptr);

    flash_attn_split<<<1024, 256, 0, stream>>>(Qa, Ka, Va, mask, Opart, mlpart);
    flash_combine<<<256, 256, 0, stream>>>(Opart, mlpart, attn);

    gemm_k1024<3><<<dim3(16, 16), 256, 0, stream>>>(attn, Wo_t, nullptr, nullptr, blk);
    bcast_out<<<16384, 256, 0, stream>>>(blk, out);
}